// Round 1
// baseline (1333.143 us; speedup 1.0000x reference)
//
#include <hip/hip_runtime.h>
#include <cstdint>

#define NODE_DIM 256
#define HALF 128
#define NJ 17

typedef __bf16 bf16x8 __attribute__((ext_vector_type(8)));
typedef float f32x4 __attribute__((ext_vector_type(4)));

// round-to-nearest-even fp32 -> bf16 bits
__device__ __forceinline__ unsigned short f2bf(float f) {
  unsigned int u = __builtin_bit_cast(unsigned int, f);
  u = (u + 0x7FFFu + ((u >> 16) & 1u)) >> 16;
  return (unsigned short)u;
}

__device__ __forceinline__ unsigned int pack2(float lo, float hi) {
  return (unsigned int)f2bf(lo) | ((unsigned int)f2bf(hi) << 16);
}

// layer-1 pair joints (groups 1..6), layer-2 pair groups
__device__ const int d_P0[6] = {5, 7, 8, 11, 13, 14};
__device__ const int d_P1[6] = {6, 9, 10, 12, 15, 16};
__device__ const int d_Q0[6] = {0, 1, 1, 1, 4, 4};
__device__ const int d_Q1[6] = {1, 2, 3, 4, 5, 6};

// ---------------------------------------------------------------------------
// Kernel 0: convert the four weight matrices fp32 -> bf16 into ws
// segments: W1_0 163840 | W1 393216 | W2 196608 | Wf 196608  (total 950272)
// ---------------------------------------------------------------------------
__global__ __launch_bounds__(256) void kconv(
    const float* __restrict__ a, const float* __restrict__ b,
    const float* __restrict__ c, const float* __restrict__ d,
    unsigned short* __restrict__ dst) {
  const int na = 163840, nb = 393216, nc = 196608, nd = 196608;
  const int total = na + nb + nc + nd;
  int i = (blockIdx.x * 256 + threadIdx.x) * 4;
  if (i >= total) return;
  const float* src;
  int off;
  if (i < na) { src = a; off = i; }
  else if (i < na + nb) { src = b; off = i - na; }
  else if (i < na + nb + nc) { src = c; off = i - na - nb; }
  else { src = d; off = i - na - nb - nc; }
  float4 v = *(const float4*)(src + off);
  uint2 p;
  p.x = pack2(v.x, v.y);
  p.y = pack2(v.z, v.w);
  *(uint2*)(dst + i) = p;
}

// ---------------------------------------------------------------------------
// Kernel 1: layer 1.  grid = ntiles*7, block = 256 (4 waves, 64 nodes/block)
// group 0: K=1280 (joints 0..4 contiguous), groups 1..6: K=512 (joint pairs)
// out1[n][g][128] bf16, relu(x@W^T+b)
// ---------------------------------------------------------------------------
__global__ __launch_bounds__(256) void k1_layer1(
    const float* __restrict__ upd,
    const unsigned short* __restrict__ w10,
    const unsigned short* __restrict__ w1,
    const float* __restrict__ b10,
    const float* __restrict__ b1,
    unsigned short* __restrict__ out1,
    int N, int ntiles) {
  __shared__ unsigned short sA[64 * 72];   // 64 nodes x 64 k, pad +8
  __shared__ unsigned short sW[128 * 72];  // 128 cols x 64 k, pad +8

  const int tile = blockIdx.x % ntiles;
  const int g = blockIdx.x / ntiles;
  const int t = threadIdx.x;
  const int lane = t & 63;
  const int wv = t >> 6;
  const int l16 = lane & 15;
  const int quad = lane >> 4;
  const int node0 = tile * 64;

  const int K = (g == 0) ? 1280 : 512;
  const unsigned short* W = (g == 0) ? w10 : (w1 + (size_t)(g - 1) * 128 * 512);

  // staging coordinates
  const int ar = t >> 2, al = t & 3;  // sA: row 0..63, 16-float slot 0..3
  const int wr = t >> 1, wh = t & 1;  // sW: row 0..127, 32-elem slot 0..1

  f32x4 acc[8];
#pragma unroll
  for (int i = 0; i < 8; ++i) acc[i] = (f32x4){0.f, 0.f, 0.f, 0.f};

  int n = node0 + ar;
  if (n >= N) n = N - 1;

  const int nchunks = K >> 6;
  for (int kc = 0; kc < nchunks; ++kc) {
    const int kabs = kc << 6;
    int j;
    if (g == 0) j = kabs >> 8;
    else j = (kabs < 256) ? d_P0[g - 1] : d_P1[g - 1];

    const float* src = upd + ((size_t)n * NJ + j) * NODE_DIM + (kabs & 255) + al * 16;
    float4 f0 = *(const float4*)(src + 0);
    float4 f1 = *(const float4*)(src + 4);
    float4 f2 = *(const float4*)(src + 8);
    float4 f3 = *(const float4*)(src + 12);
    const uint4* wsrc = (const uint4*)(W + (size_t)wr * K + kabs + wh * 32);
    uint4 q0 = wsrc[0], q1 = wsrc[1], q2 = wsrc[2], q3 = wsrc[3];

    __syncthreads();  // protect previous iteration's LDS reads
    uint4 pa0, pa1;
    pa0.x = pack2(f0.x, f0.y); pa0.y = pack2(f0.z, f0.w);
    pa0.z = pack2(f1.x, f1.y); pa0.w = pack2(f1.z, f1.w);
    pa1.x = pack2(f2.x, f2.y); pa1.y = pack2(f2.z, f2.w);
    pa1.z = pack2(f3.x, f3.y); pa1.w = pack2(f3.z, f3.w);
    *(uint4*)(sA + ar * 72 + al * 16) = pa0;
    *(uint4*)(sA + ar * 72 + al * 16 + 8) = pa1;
    uint4* dW = (uint4*)(sW + wr * 72 + wh * 32);
    dW[0] = q0; dW[1] = q1; dW[2] = q2; dW[3] = q3;
    __syncthreads();

#pragma unroll
    for (int kk = 0; kk < 64; kk += 32) {
      bf16x8 a = *(const bf16x8*)(sA + (wv * 16 + l16) * 72 + kk + quad * 8);
#pragma unroll
      for (int nt = 0; nt < 8; ++nt) {
        bf16x8 b = *(const bf16x8*)(sW + (nt * 16 + l16) * 72 + kk + quad * 8);
        acc[nt] = __builtin_amdgcn_mfma_f32_16x16x32_bf16(a, b, acc[nt], 0, 0, 0);
      }
    }
  }

  const float* bias = (g == 0) ? b10 : (b1 + (g - 1) * HALF);
#pragma unroll
  for (int nt = 0; nt < 8; ++nt) {
    const float bv = bias[nt * 16 + l16];
#pragma unroll
    for (int r = 0; r < 4; ++r) {
      const int node = node0 + wv * 16 + quad * 4 + r;
      if (node < N) {
        float v = acc[nt][r] + bv;
        v = v > 0.f ? v : 0.f;
        out1[(size_t)node * 896 + g * 128 + nt * 16 + l16] = f2bf(v);
      }
    }
  }
}

// ---------------------------------------------------------------------------
// Kernel 2: layer 2.  grid = ntiles*6.  K=256 from out1 pair gather.
// out2[n][g][128] bf16
// ---------------------------------------------------------------------------
__global__ __launch_bounds__(256) void k2_layer2(
    const unsigned short* __restrict__ out1,
    const unsigned short* __restrict__ w2,
    const float* __restrict__ b2,
    unsigned short* __restrict__ out2,
    int N, int ntiles) {
  __shared__ unsigned short sA[64 * 72];
  __shared__ unsigned short sW[128 * 72];

  const int tile = blockIdx.x % ntiles;
  const int g = blockIdx.x / ntiles;
  const int t = threadIdx.x;
  const int lane = t & 63;
  const int wv = t >> 6;
  const int l16 = lane & 15;
  const int quad = lane >> 4;
  const int node0 = tile * 64;

  const unsigned short* W = w2 + (size_t)g * 128 * 256;
  const int ar = t >> 2, al = t & 3;
  const int wr = t >> 1, wh = t & 1;

  f32x4 acc[8];
#pragma unroll
  for (int i = 0; i < 8; ++i) acc[i] = (f32x4){0.f, 0.f, 0.f, 0.f};

  int n = node0 + ar;
  if (n >= N) n = N - 1;
  const int p0 = d_Q0[g], p1 = d_Q1[g];

  for (int kc = 0; kc < 4; ++kc) {
    const int kabs = kc << 6;
    const int grp = (kabs < 128) ? p0 : p1;
    const unsigned short* srcA = out1 + (size_t)n * 896 + grp * 128 + (kabs & 127) + al * 16;
    const uint4* asrc = (const uint4*)srcA;
    uint4 va0 = asrc[0], va1 = asrc[1];
    const uint4* wsrc = (const uint4*)(W + (size_t)wr * 256 + kabs + wh * 32);
    uint4 q0 = wsrc[0], q1 = wsrc[1], q2 = wsrc[2], q3 = wsrc[3];

    __syncthreads();
    uint4* dA = (uint4*)(sA + ar * 72 + al * 16);
    dA[0] = va0; dA[1] = va1;
    uint4* dW = (uint4*)(sW + wr * 72 + wh * 32);
    dW[0] = q0; dW[1] = q1; dW[2] = q2; dW[3] = q3;
    __syncthreads();

#pragma unroll
    for (int kk = 0; kk < 64; kk += 32) {
      bf16x8 a = *(const bf16x8*)(sA + (wv * 16 + l16) * 72 + kk + quad * 8);
#pragma unroll
      for (int nt = 0; nt < 8; ++nt) {
        bf16x8 b = *(const bf16x8*)(sW + (nt * 16 + l16) * 72 + kk + quad * 8);
        acc[nt] = __builtin_amdgcn_mfma_f32_16x16x32_bf16(a, b, acc[nt], 0, 0, 0);
      }
    }
  }

  const float* bias = b2 + g * HALF;
#pragma unroll
  for (int nt = 0; nt < 8; ++nt) {
    const float bv = bias[nt * 16 + l16];
#pragma unroll
    for (int r = 0; r < 4; ++r) {
      const int node = node0 + wv * 16 + quad * 4 + r;
      if (node < N) {
        float v = acc[nt][r] + bv;
        v = v > 0.f ? v : 0.f;
        out2[(size_t)node * 768 + g * 128 + nt * 16 + l16] = f2bf(v);
      }
    }
  }
}

// ---------------------------------------------------------------------------
// Kernel 3: final.  grid = ntiles.  K=768 contiguous, Nout=256 (16 n-tiles).
// ---------------------------------------------------------------------------
__global__ __launch_bounds__(256) void k3_final(
    const unsigned short* __restrict__ out2,
    const unsigned short* __restrict__ wf,
    const float* __restrict__ bf_,
    float* __restrict__ out,
    int N) {
  __shared__ unsigned short sA[64 * 72];
  __shared__ unsigned short sW[256 * 72];  // 36 KiB

  const int t = threadIdx.x;
  const int lane = t & 63;
  const int wv = t >> 6;
  const int l16 = lane & 15;
  const int quad = lane >> 4;
  const int node0 = blockIdx.x * 64;

  const int ar = t >> 2, al = t & 3;

  f32x4 acc[16];
#pragma unroll
  for (int i = 0; i < 16; ++i) acc[i] = (f32x4){0.f, 0.f, 0.f, 0.f};

  int n = node0 + ar;
  if (n >= N) n = N - 1;

  for (int kc = 0; kc < 12; ++kc) {
    const int kabs = kc << 6;
    const uint4* asrc = (const uint4*)(out2 + (size_t)n * 768 + kabs + al * 16);
    uint4 va0 = asrc[0], va1 = asrc[1];
    const uint4* wsrc = (const uint4*)(wf + (size_t)t * 768 + kabs);
    uint4 q0 = wsrc[0], q1 = wsrc[1], q2 = wsrc[2], q3 = wsrc[3];
    uint4 q4 = wsrc[4], q5 = wsrc[5], q6 = wsrc[6], q7 = wsrc[7];

    __syncthreads();
    uint4* dA = (uint4*)(sA + ar * 72 + al * 16);
    dA[0] = va0; dA[1] = va1;
    uint4* dW = (uint4*)(sW + t * 72);
    dW[0] = q0; dW[1] = q1; dW[2] = q2; dW[3] = q3;
    dW[4] = q4; dW[5] = q5; dW[6] = q6; dW[7] = q7;
    __syncthreads();

#pragma unroll
    for (int kk = 0; kk < 64; kk += 32) {
      bf16x8 a = *(const bf16x8*)(sA + (wv * 16 + l16) * 72 + kk + quad * 8);
#pragma unroll
      for (int nt = 0; nt < 16; ++nt) {
        bf16x8 b = *(const bf16x8*)(sW + (nt * 16 + l16) * 72 + kk + quad * 8);
        acc[nt] = __builtin_amdgcn_mfma_f32_16x16x32_bf16(a, b, acc[nt], 0, 0, 0);
      }
    }
  }

#pragma unroll
  for (int nt = 0; nt < 16; ++nt) {
    const float bv = bf_[nt * 16 + l16];
#pragma unroll
    for (int r = 0; r < 4; ++r) {
      const int node = node0 + wv * 16 + quad * 4 + r;
      if (node < N) {
        float v = acc[nt][r] + bv;
        v = v > 0.f ? v : 0.f;
        out[(size_t)node * 256 + nt * 16 + l16] = v;
      }
    }
  }
}

// ---------------------------------------------------------------------------
extern "C" void kernel_launch(void* const* d_in, const int* in_sizes, int n_in,
                              void* d_out, int out_size, void* d_ws, size_t ws_size,
                              hipStream_t stream) {
  const float* upd = (const float*)d_in[0];
  const float* W10f = (const float*)d_in[1];
  const float* b10 = (const float*)d_in[2];
  const float* W1f = (const float*)d_in[3];
  const float* b1 = (const float*)d_in[4];
  const float* W2f = (const float*)d_in[5];
  const float* b2 = (const float*)d_in[6];
  const float* Wff = (const float*)d_in[7];
  const float* bff = (const float*)d_in[8];

  const int N = in_sizes[0] / (NJ * NODE_DIM);
  const int ntiles = (N + 63) / 64;

  unsigned short* wbf = (unsigned short*)d_ws;
  unsigned short* w10 = wbf;
  unsigned short* w1 = wbf + 163840;
  unsigned short* w2 = wbf + 163840 + 393216;
  unsigned short* wf = wbf + 163840 + 393216 + 196608;
  unsigned short* out1 = (unsigned short*)((char*)d_ws + (size_t)(2u << 20));
  unsigned short* out2 = out1 + (size_t)N * 896;

  // weights: 950272 elems / 4 per thread = 237568 threads
  kconv<<<(237568 + 255) / 256, 256, 0, stream>>>(W10f, W1f, W2f, Wff, wbf);
  k1_layer1<<<ntiles * 7, 256, 0, stream>>>(upd, w10, w1, b10, b1, out1, N, ntiles);
  k2_layer2<<<ntiles * 6, 256, 0, stream>>>(out1, w2, b2, out2, N, ntiles);
  k3_final<<<ntiles, 256, 0, stream>>>(out2, wf, bff, (float*)d_out, N);
}